// Round 12
// baseline (168.997 us; speedup 1.0000x reference)
//
#include <hip/hip_runtime.h>
#include <stdint.h>

typedef __attribute__((ext_vector_type(8))) short short8;   // 8 x bf16 (4 VGPR)
typedef __attribute__((ext_vector_type(4))) short short4v;
typedef __attribute__((ext_vector_type(2))) short short2v;
typedef __attribute__((ext_vector_type(4))) float f32x4;
typedef __attribute__((ext_vector_type(8))) __bf16 bf16x8;

__device__ __forceinline__ short f2bf(float f) {            // RNE (prep kernels)
  unsigned u = __builtin_bit_cast(unsigned, f);
  u = (u + 0x7FFFu + ((u >> 16) & 1u)) >> 16;
  return (short)u;
}

__device__ __forceinline__ short f2bf_fast(float f) {       // round-half-up (flash P)
  return (short)((__builtin_bit_cast(unsigned, f) + 0x8000u) >> 16);
}

__device__ __forceinline__ f32x4 mfma16(short8 a, short8 b, f32x4 c) {
  return __builtin_amdgcn_mfma_f32_16x16x32_bf16(
      __builtin_bit_cast(bf16x8, a), __builtin_bit_cast(bf16x8, b), c, 0, 0, 0);
}

// async global->LDS, 16B per lane. lds dest must be wave-uniform; HW writes base + lane*16.
__device__ __forceinline__ void gload_lds16(const void* g, void* l) {
  __builtin_amdgcn_global_load_lds(
      (const __attribute__((address_space(1))) unsigned int*)g,
      (__attribute__((address_space(3))) unsigned int*)l, 16, 0, 0);
}

// ---------------- fused convert: x, W_dkv, W_o -> bf16 (one launch) ----------------
__global__ __launch_bounds__(256) void conv3(
    const float* __restrict__ x, const float* __restrict__ wdkv,
    const float* __restrict__ wo,
    short* __restrict__ xb, short* __restrict__ wdkvb, short* __restrict__ wob) {
  int i = blockIdx.x * 256 + threadIdx.x;           // quads; 13312 blocks exact
  const float* in; short* out; int off;
  if (i < 2097152)      { in = x;    out = xb;    off = i; }
  else if (i < 2359296) { in = wdkv; out = wdkvb; off = i - 2097152; }
  else                  { in = wo;   out = wob;   off = i - 2359296; }
  f32x4 v = ((const f32x4*)in)[off];
  short4v o;
  o[0] = f2bf(v[0]); o[1] = f2bf(v[1]); o[2] = f2bf(v[2]); o[3] = f2bf(v[3]);
  ((short4v*)out)[off] = o;
}

// ---------------- batched LDS-tiled f32->bf16 transpose of the 3 weight mats ----------
__global__ __launch_bounds__(256) void trans_w3(
    const float* __restrict__ Wuk, const float* __restrict__ Wdq,
    const float* __restrict__ Wuv,
    short* __restrict__ wukT, short* __restrict__ wdqT, short* __restrict__ wuvT)
{
  const int z = blockIdx.y;
  const float* in; short* out; int R, C;
  if (z == 0)      { in = Wuk; out = wukT; R = 2048; C = 512; }
  else if (z == 1) { in = Wdq; out = wdqT; R = 512;  C = 2048; }
  else             { in = Wuv; out = wuvT; R = 2048; C = 512; }
  const int tpc = C >> 6;
  const int r0 = (blockIdx.x / tpc) << 6, c0 = (blockIdx.x % tpc) << 6;
  __shared__ float tile[64][65];
  const int tid = threadIdx.x;
#pragma unroll
  for (int i = 0; i < 4; ++i) {
    int idx = tid + i * 256;                        // 1024 float4 units
    int row = idx >> 4, col4 = (idx & 15) * 4;
    f32x4 v = *(const f32x4*)(in + (size_t)(r0 + row) * C + c0 + col4);
    tile[row][col4] = v[0]; tile[row][col4 + 1] = v[1];
    tile[row][col4 + 2] = v[2]; tile[row][col4 + 3] = v[3];
  }
  __syncthreads();
#pragma unroll
  for (int i = 0; i < 4; ++i) {
    int idx = tid + i * 256;                        // 1024 short4 units
    int crow = idx >> 4, r4 = (idx & 15) * 4;
    short4v o;
    o[0] = f2bf(tile[r4][crow]);     o[1] = f2bf(tile[r4 + 1][crow]);
    o[2] = f2bf(tile[r4 + 2][crow]); o[3] = f2bf(tile[r4 + 3][crow]);
    *(short4v*)(out + (size_t)(c0 + crow) * R + r0 + r4) = o;
  }
}

// vabsT[h][d][l] = vflat[l][h*128+d]  — LDS-tiled. grid (32, 8); 256 threads.
__global__ __launch_bounds__(256) void trans_vabs(const short* __restrict__ in,
                                                  short* __restrict__ out) {
  const int c0 = blockIdx.x << 6, l0 = blockIdx.y << 6;
  __shared__ short tile[64][66];
  const int tid = threadIdx.x;
#pragma unroll
  for (int i = 0; i < 8; ++i) {
    int idx = tid + i * 256;                        // 2048 short2 units
    int row = idx >> 5, col2 = (idx & 31) * 2;
    short2v v = *(const short2v*)(in + (size_t)(l0 + row) * 2048 + c0 + col2);
    tile[row][col2] = v[0]; tile[row][col2 + 1] = v[1];
  }
  __syncthreads();
  const int h = c0 >> 7, d0 = c0 & 127;
  short* ob = out + ((size_t)h << 16) + (size_t)d0 * 512 + l0;
#pragma unroll
  for (int i = 0; i < 8; ++i) {
    int idx = tid + i * 256;
    int crow = idx >> 5, l2 = (idx & 31) * 2;
    short2v v;
    v[0] = tile[l2][crow]; v[1] = tile[l2 + 1][crow];
    *(short2v*)(ob + (size_t)crow * 512 + l2) = v;
  }
}

// ---------------- shared NT GEMM bodies ----------------

__device__ __forceinline__ void gemm128_body(
    const short* A, const short* B, float* Cf, short* Cb,
    int K, int lda, int ldb, int ldc, int bx, int by, float scale)
{
  const int tid = threadIdx.x, wid = tid >> 6, L = tid & 63;
  const int g = L >> 4, r16 = L & 15, wr = wid >> 1, wc = wid & 1;
  const int rl = L >> 3, ru = L & 7;

  __shared__ short Asm[128 * 64], Bsm[128 * 64];
  char* Ab = (char*)Asm;
  char* Bb = (char*)Bsm;

  const f32x4 fz = {0.f, 0.f, 0.f, 0.f};
  f32x4 acc[4][4];
#pragma unroll
  for (int m = 0; m < 4; ++m)
#pragma unroll
    for (int n = 0; n < 4; ++n) acc[m][n] = fz;

  const int aRow0 = bx * 128, bRow0 = by * 128;

  for (int kt = 0; kt < K; kt += 64) {
#pragma unroll
    for (int i = 0; i < 4; ++i) {
      int row = i * 32 + wid * 8 + rl;
      gload_lds16(A + (size_t)(aRow0 + row) * lda + kt + ((ru ^ rl) * 8),
                  Ab + (i * 32 + wid * 8) * 128);
    }
#pragma unroll
    for (int i = 0; i < 4; ++i) {
      int row = i * 32 + wid * 8 + rl;
      gload_lds16(B + (size_t)(bRow0 + row) * ldb + kt + ((ru ^ rl) * 8),
                  Bb + (i * 32 + wid * 8) * 128);
    }
    __syncthreads();
#pragma unroll
    for (int kk = 0; kk < 2; ++kk) {
      short8 a[4], b2[4];
#pragma unroll
      for (int m = 0; m < 4; ++m) {
        int row = wr * 64 + m * 16 + r16;
        a[m] = *(const short8*)(Ab + row * 128 + (((kk * 4 + g) ^ (row & 7)) << 4));
      }
#pragma unroll
      for (int n = 0; n < 4; ++n) {
        int row = wc * 64 + n * 16 + r16;
        b2[n] = *(const short8*)(Bb + row * 128 + (((kk * 4 + g) ^ (row & 7)) << 4));
      }
#pragma unroll
      for (int m = 0; m < 4; ++m)
#pragma unroll
        for (int n = 0; n < 4; ++n) acc[m][n] = mfma16(a[m], b2[n], acc[m][n]);
    }
    __syncthreads();
  }

#pragma unroll
  for (int m = 0; m < 4; ++m) {
    int row0 = aRow0 + wr * 64 + m * 16 + g * 4;
#pragma unroll
    for (int n = 0; n < 4; ++n) {
      int col = bRow0 + wc * 64 + n * 16 + r16;
#pragma unroll
      for (int e = 0; e < 4; ++e) {
        long idx = (long)(row0 + e) * ldc + col;
        float v = acc[m][n][e] * scale;
        if (Cf) Cf[idx] = v;
        if (Cb) Cb[idx] = f2bf(v);
      }
    }
  }
}

__device__ __forceinline__ void gemm64_body(
    const short* A, const short* B, float* Cf, short* Cb,
    int K, int lda, int ldb, int ldc, int bx, int by, float scale)
{
  const int tid = threadIdx.x, wid = tid >> 6, L = tid & 63;
  const int g = L >> 4, r16 = L & 15, wr = wid >> 1, wc = wid & 1;

  __shared__ short Asm[64 * 64], Bsm[64 * 64];
  char* Ab = (char*)Asm;
  char* Bb = (char*)Bsm;

  const f32x4 fz = {0.f, 0.f, 0.f, 0.f};
  f32x4 acc[2][2] = {{fz, fz}, {fz, fz}};
  const int aRow0 = bx * 64, bRow0 = by * 64;

  for (int kt = 0; kt < K; kt += 64) {
#pragma unroll
    for (int i = 0; i < 2; ++i) {
      int ug = i * 256 + wid * 64;
      int row = (ug + L) >> 3, u = (ug + L) & 7;
      gload_lds16(A + (size_t)(aRow0 + row) * lda + kt + ((u ^ (row & 7)) * 8),
                  Ab + ug * 16);
    }
#pragma unroll
    for (int i = 0; i < 2; ++i) {
      int ug = i * 256 + wid * 64;
      int row = (ug + L) >> 3, u = (ug + L) & 7;
      gload_lds16(B + (size_t)(bRow0 + row) * ldb + kt + ((u ^ (row & 7)) * 8),
                  Bb + ug * 16);
    }
    __syncthreads();
#pragma unroll
    for (int kk = 0; kk < 2; ++kk) {
      short8 a[2], b2[2];
#pragma unroll
      for (int m = 0; m < 2; ++m) {
        int row = wr * 32 + m * 16 + r16;
        a[m] = *(const short8*)(Ab + row * 128 + (((kk * 4 + g) ^ (row & 7)) << 4));
      }
#pragma unroll
      for (int n = 0; n < 2; ++n) {
        int row = wc * 32 + n * 16 + r16;
        b2[n] = *(const short8*)(Bb + row * 128 + (((kk * 4 + g) ^ (row & 7)) << 4));
      }
#pragma unroll
      for (int m = 0; m < 2; ++m)
#pragma unroll
        for (int n = 0; n < 2; ++n) acc[m][n] = mfma16(a[m], b2[n], acc[m][n]);
    }
    __syncthreads();
  }

#pragma unroll
  for (int m = 0; m < 2; ++m) {
    int row0 = aRow0 + wr * 32 + m * 16 + g * 4;
#pragma unroll
    for (int n = 0; n < 2; ++n) {
      int col = bRow0 + wc * 32 + n * 16 + r16;
#pragma unroll
      for (int e = 0; e < 4; ++e) {
        long idx = (long)(row0 + e) * ldc + col;
        float v = acc[m][n][e] * scale;
        if (Cf) Cf[idx] = v;
        if (Cb) Cb[idx] = f2bf(v);
      }
    }
  }
}

// ---- fused independent prep GEMMs at 128² tiles (R11: 64² tiles were 4x staging-
// inefficient; 208 blocks of 128² = one round per CU at full tile efficiency) ----
// m1 (16 blk) | vflat (64 blk) | ckv (128 blk); all K=2048, lda=ldb=2048.
__global__ __launch_bounds__(256) void gemm_jobs3(
    const short* __restrict__ wukT, const short* __restrict__ wuvT,
    const short* __restrict__ wo, const short* __restrict__ x_bf,
    const short* __restrict__ wdkv,
    short* __restrict__ m1, short* __restrict__ vflat,
    float* __restrict__ ckv_f, short* __restrict__ ckvb)
{
  const int bid = blockIdx.x;
  const short *A, *B; short* Cb; float* Cf; int bx, by, ldc;
  if (bid < 16)      { A = wukT; B = wukT; Cb = m1;    Cf = nullptr;
                       bx = bid >> 2;        by = bid & 3;         ldc = 512; }
  else if (bid < 80) { A = wuvT; B = wo;   Cb = vflat; Cf = nullptr;
                       bx = (bid - 16) >> 4; by = (bid - 16) & 15; ldc = 2048; }
  else               { A = x_bf; B = wdkv; Cb = ckvb;  Cf = ckv_f;
                       bx = (bid - 80) >> 2; by = (bid - 80) & 3;  ldc = 512; }
  gemm128_body(A, B, Cf, Cb, 2048, 2048, 2048, ldc, bx, by, 1.0f);
}

// kabs = W_dq^T @ M1, scale = log2(e)/sqrt(128) folded (flash uses exp2 directly;
// the constant softmax shift cancels exactly in y = acc/l).
__global__ __launch_bounds__(256) void gemm_kabs(
    const short* __restrict__ wdqT, const short* __restrict__ m1,
    short* __restrict__ kabs)
{
  gemm64_body(wdqT, m1, nullptr, kabs, 512, 512, 512, 512,
              blockIdx.x, blockIdx.y, 0.08838834764831845f * 1.4426950408889634f);
}

// ---- fused keff + veff: z<32 -> k_effT[bh][s][d]; z>=32 -> v_effT[bh][d][s] ----
__global__ __launch_bounds__(256) void gemm_keffveff(
    const short* __restrict__ ckvb, const short* __restrict__ kabs,
    const short* __restrict__ vabsT,
    short* __restrict__ keffT, short* __restrict__ veffT)
{
  const int bz = blockIdx.z;
  const short *A, *B; short* C; int ldc, bx, by;
  if (bz < 32) {
    int b = bz >> 4, h = bz & 15;
    A = ckvb + (size_t)b * 2048 * 512;
    B = kabs + (size_t)h * 128 * 512;
    C = keffT + (size_t)bz * 2048 * 128;
    ldc = 128; bx = blockIdx.x; by = 0;
  } else {
    int bh = bz - 32, b = bh >> 4, h = bh & 15;
    A = vabsT + (size_t)h * 128 * 512;
    B = ckvb + (size_t)b * 2048 * 512;
    C = veffT + (size_t)bh * 128 * 2048;
    ldc = 2048; bx = 0; by = blockIdx.x;
  }
  gemm128_body(A, B, nullptr, C, 512, 512, 512, ldc, bx, by, 1.0f);
}

// ---------------- causal flash attention, D=128, balanced row-half blocks ----------
// R11 counters: OccupancyPercent 13% = ~4 waves/CU average, NOT the 8 the shape
// implies: the (f, f+256) complementary pairing runs a 2-kt block next to a 32-kt
// block, so the CU spends most time with ONE 4-wave WG (1 wave/SIMD -> the ~800cy
// per-kt serial chain is fully latency-exposed). R12 fix: EVERY block gets the same
// work. Block = (pair p, bh, rowhalf r): processes rows [r*64, r*64+64) of qt=p,
// then of qt=15-p, sequentially. Causality: rows [0,64) need 2qt+1 key-tiles, rows
// [64,128) need 2qt+2 -> per-block total = 32+2r kt. 4 waves x 16 q-rows; acc
// drops to 32 VGPR; LDS 72K (P 8K + 2x32K dbuf) -> 2 WG/CU, 8 waves/CU steady.
__global__ __launch_bounds__(256) void flash_d128(
    const short* __restrict__ x_bf,  // [2][2048][2048]
    const short* __restrict__ kT,    // [32][2048][128]
    const short* __restrict__ vT,    // [32][128][2048]
    float* __restrict__ y)           // [2][2048][2048]
{
  const int f = blockIdx.x;
  const int r = f & 1, bh = (f >> 1) & 31, pp = f >> 6;
  const int b = bh >> 4, h = bh & 15;
  const int tid = threadIdx.x, wid = tid >> 6, L = tid & 63, g = L >> 4, r16 = L & 15;

  __shared__ char lds[73728];        // [P 4x2K][buf0: K 16K | V 16K][buf1: K | V]

  const char* kbase = (const char*)(kT + (size_t)bh * (2048 * 128));
  const char* vbase = (const char*)(vT + (size_t)bh * (128 * 2048));

  // hoisted lane-invariant LDS byte offsets
  int kfo[4], vfo[2], pao[2], pwo[4];
#pragma unroll
  for (int ks = 0; ks < 4; ++ks)
    kfo[ks] = 8192 + r16 * 256 + (((ks * 4 + g) ^ r16) << 4);
#pragma unroll
  for (int kk = 0; kk < 2; ++kk) {
    vfo[kk] = 24576 + r16 * 128 + (((kk * 4 + g) ^ (r16 & 7)) << 4);
    pao[kk] = wid * 2048 + r16 * 128 + (((kk * 4 + g) ^ (r16 & 7)) << 4);
  }
#pragma unroll
  for (int e = 0; e < 4; ++e) {
    int qrow = g * 4 + e;
    pwo[e] = wid * 2048 + qrow * 128 + ((r16 * 2) ^ ((qrow & 7) << 4));
  }

  // staging lane offsets
  const int kLaneOff = (wid * 4 + g) * 256 + ((r16 ^ (wid * 4 + g)) << 4);
  const size_t vLaneOff = (size_t)(wid * 8 + (L >> 3)) * 4096 + (((L & 7) ^ (L >> 3)) << 4);

  short8 ones;
#pragma unroll
  for (int i = 0; i < 8; ++i) ones[i] = (short)0x3F80;
  const f32x4 fz = {0.f, 0.f, 0.f, 0.f};

  for (int seg = 0; seg < 2; ++seg) {
    const int qt = seg ? 15 - pp : pp;
    const int qw = qt * 128 + r * 64 + wid * 16;   // this wave's 16 q-rows
    const int nkt = 2 * qt + 1 + r;

    short8 qf[4];
#pragma unroll
    for (int ks = 0; ks < 4; ++ks)
      qf[ks] = *(const short8*)(x_bf +
          (size_t)(b * 2048 + qw + r16) * 2048 + h * 128 + ks * 32 + g * 8);

    f32x4 acc[8];
#pragma unroll
    for (int n = 0; n < 8; ++n) acc[n] = fz;
    f32x4 acc_l = fz;                  // softmax denominator via ones-MFMA

    const char* kp = kbase + kLaneOff;
    const char* vp = vbase + vLaneOff;

    auto stage = [&](int c) {
      const int base = 8192 + c * 32768 + wid * 1024;
#pragma unroll
      for (int i = 0; i < 4; ++i)
        gload_lds16(kp + i * 4096, lds + base + i * 4096);
#pragma unroll
      for (int i = 0; i < 4; ++i)
        gload_lds16(vp + (size_t)i * 131072, lds + base + 16384 + i * 4096);
      kp += 16384;                     // 64 keys * 256B
      vp += 128;                       // 64 keys * 2B along s
    };

    stage(0);

    for (int kt = 0; kt < nkt; ++kt) {
      const int c = kt & 1, co = c * 32768, s0 = kt * 64;

      if (kt + 1 < nkt) {
        stage(c ^ 1);
        asm volatile("s_waitcnt vmcnt(8)" ::: "memory");
      } else {
        asm volatile("s_waitcnt vmcnt(0)" ::: "memory");
      }
      __builtin_amdgcn_s_barrier();

      // QK^T: S[16 q][64 s]
      f32x4 s[4] = {fz, fz, fz, fz};
      __builtin_amdgcn_s_setprio(1);
#pragma unroll
      for (int ks = 0; ks < 4; ++ks) {
        const char* kb = lds + co + kfo[ks];
#pragma unroll
        for (int n = 0; n < 4; ++n)
          s[n] = mfma16(qf[ks], *(const short8*)(kb + n * 4096), s[n]);
      }
      __builtin_amdgcn_s_setprio(0);

      if (s0 + 63 > qw) {              // causal mask (straddling tiles only)
#pragma unroll
        for (int n = 0; n < 4; ++n)
#pragma unroll
          for (int e = 0; e < 4; ++e)
            if (s0 + n * 16 + r16 > qw + g * 4 + e) s[n][e] = -3e38f;
      }

      // p = exp2(S) (shift-free), pack + LDS write
#pragma unroll
      for (int n = 0; n < 4; ++n)
#pragma unroll
        for (int e = 0; e < 4; ++e) {
          float p = exp2f(s[n][e]);
          *(short*)(lds + (pwo[e] ^ (n << 5))) = f2bf_fast(p);
        }
      short8 pa[2];
#pragma unroll
      for (int kk = 0; kk < 2; ++kk)
        pa[kk] = *(const short8*)(lds + pao[kk]);

      // PV + denominator
      __builtin_amdgcn_s_setprio(1);
#pragma unroll
      for (int kk = 0; kk < 2; ++kk) acc_l = mfma16(pa[kk], ones, acc_l);
#pragma unroll
      for (int kk = 0; kk < 2; ++kk) {
        const char* vb = lds + co + vfo[kk];
#pragma unroll
        for (int n = 0; n < 8; ++n)
          acc[n] = mfma16(pa[kk], *(const short8*)(vb + n * 2048), acc[n]);
      }
      __builtin_amdgcn_s_setprio(0);

      asm volatile("s_waitcnt lgkmcnt(0)" ::: "memory");
      __builtin_amdgcn_s_barrier();    // buf c reusable
    }

    // epilogue: normalize, write y fp32
    float inv[4];
#pragma unroll
    for (int e = 0; e < 4; ++e) inv[e] = 1.f / acc_l[e];
#pragma unroll
    for (int n = 0; n < 8; ++n)
#pragma unroll
      for (int e = 0; e < 4; ++e) {
        int row = qw + g * 4 + e;
        y[(size_t)(b * 2048 + row) * 2048 + h * 128 + n * 16 + r16] =
            acc[n][e] * inv[e];
      }
  }
}

// ---------------- host ----------------

extern "C" void kernel_launch(void* const* d_in, const int* in_sizes, int n_in,
                              void* d_out, int out_size, void* d_ws, size_t ws_size,
                              hipStream_t stream) {
  const float* x    = (const float*)d_in[0];
  const float* Wdq  = (const float*)d_in[1];
  const float* Wdkv = (const float*)d_in[2];
  const float* Wuk  = (const float*)d_in[3];
  const float* Wuv  = (const float*)d_in[4];
  const float* Wo   = (const float*)d_in[5];
  float* y     = (float*)d_out;                        // [2][2048][2048]
  float* ckv_f = y + (size_t)2 * 2048 * 2048;          // [2][2048][512]

  char* w = (char*)d_ws;
  auto alloc = [&](size_t bytes) { char* p = w; w += (bytes + 255) & ~(size_t)255; return p; };
  short* x_bf   = (short*)alloc((size_t)2 * 2048 * 2048 * 2);
  short* wdkv   = (short*)alloc((size_t)512 * 2048 * 2);
  short* wukT   = (short*)alloc((size_t)512 * 2048 * 2);
  short* wdqT   = (short*)alloc((size_t)2048 * 512 * 2);
  short* wuvT   = (short*)alloc((size_t)512 * 2048 * 2);
  short* wo     = (short*)alloc((size_t)2048 * 2048 * 2);
  short* m1     = (short*)alloc((size_t)512 * 512 * 2);
  short* kabs   = (short*)alloc((size_t)2048 * 512 * 2);
  short* vflat  = (short*)alloc((size_t)512 * 2048 * 2);
  short* vabsT  = (short*)alloc((size_t)16 * 128 * 512 * 2);
  short* ckvb   = (short*)alloc((size_t)2 * 2048 * 512 * 2);
  short* keffT  = (short*)alloc((size_t)32 * 2048 * 128 * 2);  // [bh][s][d]
  short* veffT  = (short*)alloc((size_t)32 * 128 * 2048 * 2);  // [bh][d][s]

  conv3<<<13312, 256, 0, stream>>>(x, Wdkv, Wo, x_bf, wdkv, wo);
  trans_w3<<<dim3(256, 3), 256, 0, stream>>>(Wuk, Wdq, Wuv, wukT, wdqT, wuvT);

  // m1 | vflat | c_kv (+ckv_f output chunk) in one 128²-tile launch
  gemm_jobs3<<<208, 256, 0, stream>>>(wukT, wuvT, wo, x_bf, wdkv,
                                      m1, vflat, ckv_f, ckvb);
  gemm_kabs<<<dim3(32, 8), 256, 0, stream>>>(wdqT, m1, kabs);
  trans_vabs<<<dim3(32, 8), 256, 0, stream>>>(vflat, vabsT);

  // k_eff + v_eff in one launch
  gemm_keffveff<<<dim3(16, 1, 64), 256, 0, stream>>>(ckvb, kabs, vabsT, keffT, veffT);

  // causal flash attention at D=128 (balanced row-half blocks); writes y fp32
  flash_d128<<<512, 256, 0, stream>>>(x_bf, keffT, veffT, y);
}

// Round 13
// 168.196 us; speedup vs baseline: 1.0048x; 1.0048x over previous
//
#include <hip/hip_runtime.h>
#include <stdint.h>

typedef __attribute__((ext_vector_type(8))) short short8;   // 8 x bf16 (4 VGPR)
typedef __attribute__((ext_vector_type(4))) short short4v;
typedef __attribute__((ext_vector_type(2))) short short2v;
typedef __attribute__((ext_vector_type(4))) float f32x4;
typedef __attribute__((ext_vector_type(8))) __bf16 bf16x8;

__device__ __forceinline__ short f2bf(float f) {            // RNE (prep kernels)
  unsigned u = __builtin_bit_cast(unsigned, f);
  u = (u + 0x7FFFu + ((u >> 16) & 1u)) >> 16;
  return (short)u;
}

__device__ __forceinline__ short f2bf_fast(float f) {       // round-half-up (flash P)
  return (short)((__builtin_bit_cast(unsigned, f) + 0x8000u) >> 16);
}

__device__ __forceinline__ f32x4 mfma16(short8 a, short8 b, f32x4 c) {
  return __builtin_amdgcn_mfma_f32_16x16x32_bf16(
      __builtin_bit_cast(bf16x8, a), __builtin_bit_cast(bf16x8, b), c, 0, 0, 0);
}

// async global->LDS, 16B per lane. lds dest must be wave-uniform; HW writes base + lane*16.
__device__ __forceinline__ void gload_lds16(const void* g, void* l) {
  __builtin_amdgcn_global_load_lds(
      (const __attribute__((address_space(1))) unsigned int*)g,
      (__attribute__((address_space(3))) unsigned int*)l, 16, 0, 0);
}

// ---------------- fused convert: x, W_dkv, W_o -> bf16 (one launch) ----------------
__global__ __launch_bounds__(256) void conv3(
    const float* __restrict__ x, const float* __restrict__ wdkv,
    const float* __restrict__ wo,
    short* __restrict__ xb, short* __restrict__ wdkvb, short* __restrict__ wob) {
  int i = blockIdx.x * 256 + threadIdx.x;           // quads; 13312 blocks exact
  const float* in; short* out; int off;
  if (i < 2097152)      { in = x;    out = xb;    off = i; }
  else if (i < 2359296) { in = wdkv; out = wdkvb; off = i - 2097152; }
  else                  { in = wo;   out = wob;   off = i - 2359296; }
  f32x4 v = ((const f32x4*)in)[off];
  short4v o;
  o[0] = f2bf(v[0]); o[1] = f2bf(v[1]); o[2] = f2bf(v[2]); o[3] = f2bf(v[3]);
  ((short4v*)out)[off] = o;
}

// ---------------- batched LDS-tiled f32->bf16 transpose of the 3 weight mats ----------
__global__ __launch_bounds__(256) void trans_w3(
    const float* __restrict__ Wuk, const float* __restrict__ Wdq,
    const float* __restrict__ Wuv,
    short* __restrict__ wukT, short* __restrict__ wdqT, short* __restrict__ wuvT)
{
  const int z = blockIdx.y;
  const float* in; short* out; int R, C;
  if (z == 0)      { in = Wuk; out = wukT; R = 2048; C = 512; }
  else if (z == 1) { in = Wdq; out = wdqT; R = 512;  C = 2048; }
  else             { in = Wuv; out = wuvT; R = 2048; C = 512; }
  const int tpc = C >> 6;
  const int r0 = (blockIdx.x / tpc) << 6, c0 = (blockIdx.x % tpc) << 6;
  __shared__ float tile[64][65];
  const int tid = threadIdx.x;
#pragma unroll
  for (int i = 0; i < 4; ++i) {
    int idx = tid + i * 256;                        // 1024 float4 units
    int row = idx >> 4, col4 = (idx & 15) * 4;
    f32x4 v = *(const f32x4*)(in + (size_t)(r0 + row) * C + c0 + col4);
    tile[row][col4] = v[0]; tile[row][col4 + 1] = v[1];
    tile[row][col4 + 2] = v[2]; tile[row][col4 + 3] = v[3];
  }
  __syncthreads();
#pragma unroll
  for (int i = 0; i < 4; ++i) {
    int idx = tid + i * 256;                        // 1024 short4 units
    int crow = idx >> 4, r4 = (idx & 15) * 4;
    short4v o;
    o[0] = f2bf(tile[r4][crow]);     o[1] = f2bf(tile[r4 + 1][crow]);
    o[2] = f2bf(tile[r4 + 2][crow]); o[3] = f2bf(tile[r4 + 3][crow]);
    *(short4v*)(out + (size_t)(c0 + crow) * R + r0 + r4) = o;
  }
}

// vabsT[h][d][l] = vflat[l][h*128+d]  — LDS-tiled. grid (32, 8); 256 threads.
__global__ __launch_bounds__(256) void trans_vabs(const short* __restrict__ in,
                                                  short* __restrict__ out) {
  const int c0 = blockIdx.x << 6, l0 = blockIdx.y << 6;
  __shared__ short tile[64][66];
  const int tid = threadIdx.x;
#pragma unroll
  for (int i = 0; i < 8; ++i) {
    int idx = tid + i * 256;                        // 2048 short2 units
    int row = idx >> 5, col2 = (idx & 31) * 2;
    short2v v = *(const short2v*)(in + (size_t)(l0 + row) * 2048 + c0 + col2);
    tile[row][col2] = v[0]; tile[row][col2 + 1] = v[1];
  }
  __syncthreads();
  const int h = c0 >> 7, d0 = c0 & 127;
  short* ob = out + ((size_t)h << 16) + (size_t)d0 * 512 + l0;
#pragma unroll
  for (int i = 0; i < 8; ++i) {
    int idx = tid + i * 256;
    int crow = idx >> 5, l2 = (idx & 31) * 2;
    short2v v;
    v[0] = tile[l2][crow]; v[1] = tile[l2 + 1][crow];
    *(short2v*)(ob + (size_t)crow * 512 + l2) = v;
  }
}

// ---------------- shared NT GEMM bodies ----------------

__device__ __forceinline__ void gemm128_body(
    const short* A, const short* B, float* Cf, short* Cb,
    int K, int lda, int ldb, int ldc, int bx, int by, float scale)
{
  const int tid = threadIdx.x, wid = tid >> 6, L = tid & 63;
  const int g = L >> 4, r16 = L & 15, wr = wid >> 1, wc = wid & 1;
  const int rl = L >> 3, ru = L & 7;

  __shared__ short Asm[128 * 64], Bsm[128 * 64];
  char* Ab = (char*)Asm;
  char* Bb = (char*)Bsm;

  const f32x4 fz = {0.f, 0.f, 0.f, 0.f};
  f32x4 acc[4][4];
#pragma unroll
  for (int m = 0; m < 4; ++m)
#pragma unroll
    for (int n = 0; n < 4; ++n) acc[m][n] = fz;

  const int aRow0 = bx * 128, bRow0 = by * 128;

  for (int kt = 0; kt < K; kt += 64) {
#pragma unroll
    for (int i = 0; i < 4; ++i) {
      int row = i * 32 + wid * 8 + rl;
      gload_lds16(A + (size_t)(aRow0 + row) * lda + kt + ((ru ^ rl) * 8),
                  Ab + (i * 32 + wid * 8) * 128);
    }
#pragma unroll
    for (int i = 0; i < 4; ++i) {
      int row = i * 32 + wid * 8 + rl;
      gload_lds16(B + (size_t)(bRow0 + row) * ldb + kt + ((ru ^ rl) * 8),
                  Bb + (i * 32 + wid * 8) * 128);
    }
    __syncthreads();
#pragma unroll
    for (int kk = 0; kk < 2; ++kk) {
      short8 a[4], b2[4];
#pragma unroll
      for (int m = 0; m < 4; ++m) {
        int row = wr * 64 + m * 16 + r16;
        a[m] = *(const short8*)(Ab + row * 128 + (((kk * 4 + g) ^ (row & 7)) << 4));
      }
#pragma unroll
      for (int n = 0; n < 4; ++n) {
        int row = wc * 64 + n * 16 + r16;
        b2[n] = *(const short8*)(Bb + row * 128 + (((kk * 4 + g) ^ (row & 7)) << 4));
      }
#pragma unroll
      for (int m = 0; m < 4; ++m)
#pragma unroll
        for (int n = 0; n < 4; ++n) acc[m][n] = mfma16(a[m], b2[n], acc[m][n]);
    }
    __syncthreads();
  }

#pragma unroll
  for (int m = 0; m < 4; ++m) {
    int row0 = aRow0 + wr * 64 + m * 16 + g * 4;
#pragma unroll
    for (int n = 0; n < 4; ++n) {
      int col = bRow0 + wc * 64 + n * 16 + r16;
#pragma unroll
      for (int e = 0; e < 4; ++e) {
        long idx = (long)(row0 + e) * ldc + col;
        float v = acc[m][n][e] * scale;
        if (Cf) Cf[idx] = v;
        if (Cb) Cb[idx] = f2bf(v);
      }
    }
  }
}

__device__ __forceinline__ void gemm64_body(
    const short* A, const short* B, float* Cf, short* Cb,
    int K, int lda, int ldb, int ldc, int bx, int by, float scale)
{
  const int tid = threadIdx.x, wid = tid >> 6, L = tid & 63;
  const int g = L >> 4, r16 = L & 15, wr = wid >> 1, wc = wid & 1;

  __shared__ short Asm[64 * 64], Bsm[64 * 64];
  char* Ab = (char*)Asm;
  char* Bb = (char*)Bsm;

  const f32x4 fz = {0.f, 0.f, 0.f, 0.f};
  f32x4 acc[2][2] = {{fz, fz}, {fz, fz}};
  const int aRow0 = bx * 64, bRow0 = by * 64;

  for (int kt = 0; kt < K; kt += 64) {
#pragma unroll
    for (int i = 0; i < 2; ++i) {
      int ug = i * 256 + wid * 64;
      int row = (ug + L) >> 3, u = (ug + L) & 7;
      gload_lds16(A + (size_t)(aRow0 + row) * lda + kt + ((u ^ (row & 7)) * 8),
                  Ab + ug * 16);
    }
#pragma unroll
    for (int i = 0; i < 2; ++i) {
      int ug = i * 256 + wid * 64;
      int row = (ug + L) >> 3, u = (ug + L) & 7;
      gload_lds16(B + (size_t)(bRow0 + row) * ldb + kt + ((u ^ (row & 7)) * 8),
                  Bb + ug * 16);
    }
    __syncthreads();
#pragma unroll
    for (int kk = 0; kk < 2; ++kk) {
      short8 a[2], b2[2];
#pragma unroll
      for (int m = 0; m < 2; ++m) {
        int row = wr * 32 + m * 16 + r16;
        a[m] = *(const short8*)(Ab + row * 128 + (((kk * 4 + g) ^ (row & 7)) << 4));
      }
#pragma unroll
      for (int n = 0; n < 2; ++n) {
        int row = wc * 32 + n * 16 + r16;
        b2[n] = *(const short8*)(Bb + row * 128 + (((kk * 4 + g) ^ (row & 7)) << 4));
      }
#pragma unroll
      for (int m = 0; m < 2; ++m)
#pragma unroll
        for (int n = 0; n < 2; ++n) acc[m][n] = mfma16(a[m], b2[n], acc[m][n]);
    }
    __syncthreads();
  }

#pragma unroll
  for (int m = 0; m < 2; ++m) {
    int row0 = aRow0 + wr * 32 + m * 16 + g * 4;
#pragma unroll
    for (int n = 0; n < 2; ++n) {
      int col = bRow0 + wc * 32 + n * 16 + r16;
#pragma unroll
      for (int e = 0; e < 4; ++e) {
        long idx = (long)(row0 + e) * ldc + col;
        float v = acc[m][n][e] * scale;
        if (Cf) Cf[idx] = v;
        if (Cb) Cb[idx] = f2bf(v);
      }
    }
  }
}

// ---- fused independent prep GEMMs, 832 x 64² tiles (R12 ERRATUM: the 208 x 128²
// retile REGRESSED ~13us — reverted to the R11 measured-good config) ----
__global__ __launch_bounds__(256) void gemm_jobs3(
    const short* __restrict__ wukT, const short* __restrict__ wuvT,
    const short* __restrict__ wo, const short* __restrict__ x_bf,
    const short* __restrict__ wdkv,
    short* __restrict__ m1, short* __restrict__ vflat,
    float* __restrict__ ckv_f, short* __restrict__ ckvb)
{
  const int bid = blockIdx.x;
  const short *A, *B; short* Cb; float* Cf; int bx, by, ldc;
  if (bid < 64)       { A = wukT; B = wukT; Cb = m1;    Cf = nullptr;
                        bx = bid >> 3;         by = bid & 7;         ldc = 512; }
  else if (bid < 320) { A = wuvT; B = wo;   Cb = vflat; Cf = nullptr;
                        bx = (bid - 64) >> 5;  by = (bid - 64) & 31; ldc = 2048; }
  else                { A = x_bf; B = wdkv; Cb = ckvb;  Cf = ckv_f;
                        bx = (bid - 320) >> 3; by = (bid - 320) & 7; ldc = 512; }
  gemm64_body(A, B, Cf, Cb, 2048, 2048, 2048, ldc, bx, by, 1.0f);
}

// kabs = W_dq^T @ M1, scale = log2(e)/sqrt(128) folded (flash uses exp2 directly;
// the constant softmax shift cancels exactly in y = acc/l).
__global__ __launch_bounds__(256) void gemm_kabs(
    const short* __restrict__ wdqT, const short* __restrict__ m1,
    short* __restrict__ kabs)
{
  gemm64_body(wdqT, m1, nullptr, kabs, 512, 512, 512, 512,
              blockIdx.x, blockIdx.y, 0.08838834764831845f * 1.4426950408889634f);
}

// ---- fused keff + veff: z<32 -> k_effT[bh][s][d]; z>=32 -> v_effT[bh][d][s] ----
__global__ __launch_bounds__(256) void gemm_keffveff(
    const short* __restrict__ ckvb, const short* __restrict__ kabs,
    const short* __restrict__ vabsT,
    short* __restrict__ keffT, short* __restrict__ veffT)
{
  const int bz = blockIdx.z;
  const short *A, *B; short* C; int ldc, bx, by;
  if (bz < 32) {
    int b = bz >> 4, h = bz & 15;
    A = ckvb + (size_t)b * 2048 * 512;
    B = kabs + (size_t)h * 128 * 512;
    C = keffT + (size_t)bz * 2048 * 128;
    ldc = 128; bx = blockIdx.x; by = 0;
  } else {
    int bh = bz - 32, b = bh >> 4, h = bh & 15;
    A = vabsT + (size_t)h * 128 * 512;
    B = ckvb + (size_t)b * 2048 * 512;
    C = veffT + (size_t)bh * 128 * 2048;
    ldc = 2048; bx = 0; by = blockIdx.x;
  }
  gemm128_body(A, B, nullptr, C, 512, 512, 512, ldc, bx, by, 1.0f);
}

// ---------------- causal flash attention, D=128, m=2 LDS-economy ----------------
// R12 census: LDS-read-throughput-bound — with 16 q-rows/wave every B-frag ds_read
// feeds ONE MFMA; 8 waves/CU × ~300cy/kt of ds_read issue >> 170cy MFMA. R13: m=2
// (32 q-rows/wave): each K/V-frag read feeds TWO MFMAs -> per-CU LDS issue per
// 128-row kt-unit drops ~1.8x. Block = 4 waves x 32 rows = full q-tile; balance via
// sequential segs (qt=p then 15-p) = constant 36 kt. Early waves' final kt is fully
// masked (exp2(-3e38)=0 -> exact). 256 blocks, LDS 80K, VGPR ~180 (R8 precedent).
__global__ __launch_bounds__(256) void flash_d128(
    const short* __restrict__ x_bf,  // [2][2048][2048]
    const short* __restrict__ kT,    // [32][2048][128]
    const short* __restrict__ vT,    // [32][128][2048]
    float* __restrict__ y)           // [2][2048][2048]
{
  const int f = blockIdx.x;          // 256 blocks
  const int bh = f & 31, pp = f >> 5;
  const int b = bh >> 4, h = bh & 15;
  const int tid = threadIdx.x, wid = tid >> 6, L = tid & 63, g = L >> 4, r16 = L & 15;

  __shared__ char lds[81920];        // [P 4x4K][buf0: K 16K | V 16K][buf1: K | V]

  const char* kbase = (const char*)(kT + (size_t)bh * (2048 * 128));
  const char* vbase = (const char*)(vT + (size_t)bh * (128 * 2048));

  // hoisted lane-invariant LDS byte offsets
  int kfo[4], vfo[2], pao[2][2], pwo[2][4];
#pragma unroll
  for (int ks = 0; ks < 4; ++ks)
    kfo[ks] = 16384 + r16 * 256 + (((ks * 4 + g) ^ r16) << 4);
#pragma unroll
  for (int kk = 0; kk < 2; ++kk)
    vfo[kk] = 32768 + r16 * 128 + (((kk * 4 + g) ^ (r16 & 7)) << 4);
#pragma unroll
  for (int m = 0; m < 2; ++m)
#pragma unroll
    for (int kk = 0; kk < 2; ++kk)
      pao[m][kk] = wid * 4096 + (m * 16 + r16) * 128 + (((kk * 4 + g) ^ (r16 & 7)) << 4);
#pragma unroll
  for (int m = 0; m < 2; ++m)
#pragma unroll
    for (int e = 0; e < 4; ++e) {
      int qrow = g * 4 + e;
      pwo[m][e] = wid * 4096 + (m * 16 + qrow) * 128 + ((r16 * 2) ^ ((qrow & 7) << 4));
    }

  // staging lane offsets (4 waves share the 16K K-tile / 16K V-tile)
  const int kLaneOff = (wid * 4 + g) * 256 + ((r16 ^ (wid * 4 + g)) << 4);
  const size_t vLaneOff = (size_t)(wid * 8 + (L >> 3)) * 4096 + (((L & 7) ^ (L >> 3)) << 4);

  short8 ones;
#pragma unroll
  for (int i = 0; i < 8; ++i) ones[i] = (short)0x3F80;
  const f32x4 fz = {0.f, 0.f, 0.f, 0.f};

  for (int seg = 0; seg < 2; ++seg) {
    const int qt = seg ? 15 - pp : pp;
    const int qw = qt * 128 + wid * 32;   // this wave's 32 q-rows
    const int nkt = 2 * qt + 2;

    short8 qf[2][4];
#pragma unroll
    for (int m = 0; m < 2; ++m)
#pragma unroll
      for (int ks = 0; ks < 4; ++ks)
        qf[m][ks] = *(const short8*)(x_bf +
            (size_t)(b * 2048 + qw + m * 16 + r16) * 2048 + h * 128 + ks * 32 + g * 8);

    f32x4 acc[2][8];
#pragma unroll
    for (int m = 0; m < 2; ++m)
#pragma unroll
      for (int n = 0; n < 8; ++n) acc[m][n] = fz;
    f32x4 acc_l[2] = {fz, fz};

    const char* kp = kbase + kLaneOff;
    const char* vp = vbase + vLaneOff;

    auto stage = [&](int c) {
      const int base = 16384 + c * 32768 + wid * 1024;
#pragma unroll
      for (int i = 0; i < 4; ++i)
        gload_lds16(kp + i * 4096, lds + base + i * 4096);
#pragma unroll
      for (int i = 0; i < 4; ++i)
        gload_lds16(vp + (size_t)i * 131072, lds + base + 16384 + i * 4096);
      kp += 16384;                     // 64 keys * 256B
      vp += 128;                       // 64 keys * 2B along s
    };

    stage(0);

    for (int kt = 0; kt < nkt; ++kt) {
      const int c = kt & 1, co = c * 32768, s0 = kt * 64;

      if (kt + 1 < nkt) {
        stage(c ^ 1);
        asm volatile("s_waitcnt vmcnt(8)" ::: "memory");
      } else {
        asm volatile("s_waitcnt vmcnt(0)" ::: "memory");
      }
      __builtin_amdgcn_s_barrier();

      // QK^T: S[32 q][64 s]; each K-frag feeds both m-subtiles
      f32x4 s[2][4] = {{fz, fz, fz, fz}, {fz, fz, fz, fz}};
      __builtin_amdgcn_s_setprio(1);
#pragma unroll
      for (int ks = 0; ks < 4; ++ks) {
        const char* kb = lds + co + kfo[ks];
#pragma unroll
        for (int n = 0; n < 4; ++n) {
          short8 kf = *(const short8*)(kb + n * 4096);
          s[0][n] = mfma16(qf[0][ks], kf, s[0][n]);
          s[1][n] = mfma16(qf[1][ks], kf, s[1][n]);
        }
      }
      __builtin_amdgcn_s_setprio(0);

      if (s0 + 63 > qw) {              // causal mask (straddling / fully-masked tiles)
#pragma unroll
        for (int m = 0; m < 2; ++m)
#pragma unroll
          for (int n = 0; n < 4; ++n)
#pragma unroll
            for (int e = 0; e < 4; ++e)
              if (s0 + n * 16 + r16 > qw + m * 16 + g * 4 + e) s[m][n][e] = -3e38f;
      }

      // p = exp2(S) (shift-free), pack + LDS write (XOR-decomposed addr)
#pragma unroll
      for (int m = 0; m < 2; ++m)
#pragma unroll
        for (int n = 0; n < 4; ++n)
#pragma unroll
          for (int e = 0; e < 4; ++e) {
            float p = exp2f(s[m][n][e]);
            *(short*)(lds + (pwo[m][e] ^ (n << 5))) = f2bf_fast(p);
          }
      short8 pa[2][2];
#pragma unroll
      for (int m = 0; m < 2; ++m)
#pragma unroll
        for (int kk = 0; kk < 2; ++kk)
          pa[m][kk] = *(const short8*)(lds + pao[m][kk]);

      // PV + denominator; each V-frag feeds both m-subtiles
      __builtin_amdgcn_s_setprio(1);
#pragma unroll
      for (int m = 0; m < 2; ++m)
#pragma unroll
        for (int kk = 0; kk < 2; ++kk) acc_l[m] = mfma16(pa[m][kk], ones, acc_l[m]);
#pragma unroll
      for (int kk = 0; kk < 2; ++kk) {
        const char* vb = lds + co + vfo[kk];
#pragma unroll
        for (int n = 0; n < 8; ++n) {
          short8 vf = *(const short8*)(vb + n * 2048);
          acc[0][n] = mfma16(pa[0][kk], vf, acc[0][n]);
          acc[1][n] = mfma16(pa[1][kk], vf, acc[1][n]);
        }
      }
      __builtin_amdgcn_s_setprio(0);

      asm volatile("s_waitcnt lgkmcnt(0)" ::: "memory");
      __builtin_amdgcn_s_barrier();    // buf c reusable
    }

    // epilogue: normalize, write y fp32
    float inv[2][4];
#pragma unroll
    for (int m = 0; m < 2; ++m)
#pragma unroll
      for (int e = 0; e < 4; ++e) inv[m][e] = 1.f / acc_l[m][e];
#pragma unroll
    for (int m = 0; m < 2; ++m)
#pragma unroll
      for (int n = 0; n < 8; ++n)
#pragma unroll
        for (int e = 0; e < 4; ++e) {
          int row = qw + m * 16 + g * 4 + e;
          y[(size_t)(b * 2048 + row) * 2048 + h * 128 + n * 16 + r16] =
              acc[m][n][e] * inv[m][e];
        }
  }
}

// ---------------- host ----------------

extern "C" void kernel_launch(void* const* d_in, const int* in_sizes, int n_in,
                              void* d_out, int out_size, void* d_ws, size_t ws_size,
                              hipStream_t stream) {
  const float* x    = (const float*)d_in[0];
  const float* Wdq  = (const float*)d_in[1];
  const float* Wdkv = (const float*)d_in[2];
  const float* Wuk  = (const float*)d_in[3];
  const float* Wuv  = (const float*)d_in[4];
  const float* Wo   = (const float*)d_in[5];
  float* y     = (float*)d_out;                        // [2][2048][2048]
  float* ckv_f = y + (size_t)2 * 2048 * 2048;          // [2][2048][512]

  char* w = (char*)d_ws;
  auto alloc = [&](size_t bytes) { char* p = w; w += (bytes + 255) & ~(size_t)255; return p; };
  short* x_bf   = (short*)alloc((size_t)2 * 2048 * 2048 * 2);
  short* wdkv   = (short*)alloc((size_t)512 * 2048 * 2);
  short* wukT   = (short*)alloc((size_t)512 * 2048 * 2);
  short* wdqT   = (short*)alloc((size_t)2048 * 512 * 2);
  short* wuvT   = (short*)alloc((size_t)512 * 2048 * 2);
  short* wo     = (short*)alloc((size_t)2048 * 2048 * 2);
  short* m1     = (short*)alloc((size_t)512 * 512 * 2);
  short* kabs   = (short*)alloc((size_t)2048 * 512 * 2);
  short* vflat  = (short*)alloc((size_t)512 * 2048 * 2);
  short* vabsT  = (short*)alloc((size_t)16 * 128 * 512 * 2);
  short* ckvb   = (short*)alloc((size_t)2 * 2048 * 512 * 2);
  short* keffT  = (short*)alloc((size_t)32 * 2048 * 128 * 2);  // [bh][s][d]
  short* veffT  = (short*)alloc((size_t)32 * 128 * 2048 * 2);  // [bh][d][s]

  conv3<<<13312, 256, 0, stream>>>(x, Wdkv, Wo, x_bf, wdkv, wo);
  trans_w3<<<dim3(256, 3), 256, 0, stream>>>(Wuk, Wdq, Wuv, wukT, wdqT, wuvT);

  // m1 | vflat | c_kv (+ckv_f output chunk) in one launch (832 x 64² — R11 config)
  gemm_jobs3<<<832, 256, 0, stream>>>(wukT, wuvT, wo, x_bf, wdkv,
                                      m1, vflat, ckv_f, ckvb);
  gemm_kabs<<<dim3(32, 8), 256, 0, stream>>>(wdqT, m1, kabs);
  trans_vabs<<<dim3(32, 8), 256, 0, stream>>>(vflat, vabsT);

  // k_eff + v_eff in one launch
  gemm_keffveff<<<dim3(16, 1, 64), 256, 0, stream>>>(ckvb, kabs, vabsT, keffT, veffT);

  // causal flash attention at D=128 (m=2, pair-sequential blocks); writes y fp32
  flash_d128<<<256, 256, 0, stream>>>(x_bf, keffT, veffT, y);
}

// Round 14
// 157.645 us; speedup vs baseline: 1.0720x; 1.0669x over previous
//
#include <hip/hip_runtime.h>
#include <stdint.h>

typedef __attribute__((ext_vector_type(8))) short short8;   // 8 x bf16 (4 VGPR)
typedef __attribute__((ext_vector_type(4))) short short4v;
typedef __attribute__((ext_vector_type(2))) short short2v;
typedef __attribute__((ext_vector_type(4))) float f32x4;
typedef __attribute__((ext_vector_type(8))) __bf16 bf16x8;

__device__ __forceinline__ short f2bf(float f) {            // RNE (prep kernels)
  unsigned u = __builtin_bit_cast(unsigned, f);
  u = (u + 0x7FFFu + ((u >> 16) & 1u)) >> 16;
  return (short)u;
}

__device__ __forceinline__ short f2bf_fast(float f) {       // round-half-up (flash P)
  return (short)((__builtin_bit_cast(unsigned, f) + 0x8000u) >> 16);
}

__device__ __forceinline__ f32x4 mfma16(short8 a, short8 b, f32x4 c) {
  return __builtin_amdgcn_mfma_f32_16x16x32_bf16(
      __builtin_bit_cast(bf16x8, a), __builtin_bit_cast(bf16x8, b), c, 0, 0, 0);
}

// async global->LDS, 16B per lane. lds dest must be wave-uniform; HW writes base + lane*16.
__device__ __forceinline__ void gload_lds16(const void* g, void* l) {
  __builtin_amdgcn_global_load_lds(
      (const __attribute__((address_space(1))) unsigned int*)g,
      (__attribute__((address_space(3))) unsigned int*)l, 16, 0, 0);
}

// ---------------- fused convert: x, W_dkv, W_o -> bf16 (one launch) ----------------
__global__ __launch_bounds__(256) void conv3(
    const float* __restrict__ x, const float* __restrict__ wdkv,
    const float* __restrict__ wo,
    short* __restrict__ xb, short* __restrict__ wdkvb, short* __restrict__ wob) {
  int i = blockIdx.x * 256 + threadIdx.x;           // quads; 13312 blocks exact
  const float* in; short* out; int off;
  if (i < 2097152)      { in = x;    out = xb;    off = i; }
  else if (i < 2359296) { in = wdkv; out = wdkvb; off = i - 2097152; }
  else                  { in = wo;   out = wob;   off = i - 2359296; }
  f32x4 v = ((const f32x4*)in)[off];
  short4v o;
  o[0] = f2bf(v[0]); o[1] = f2bf(v[1]); o[2] = f2bf(v[2]); o[3] = f2bf(v[3]);
  ((short4v*)out)[off] = o;
}

// ---------------- batched LDS-tiled f32->bf16 transpose of the 3 weight mats ----------
__global__ __launch_bounds__(256) void trans_w3(
    const float* __restrict__ Wuk, const float* __restrict__ Wdq,
    const float* __restrict__ Wuv,
    short* __restrict__ wukT, short* __restrict__ wdqT, short* __restrict__ wuvT)
{
  const int z = blockIdx.y;
  const float* in; short* out; int R, C;
  if (z == 0)      { in = Wuk; out = wukT; R = 2048; C = 512; }
  else if (z == 1) { in = Wdq; out = wdqT; R = 512;  C = 2048; }
  else             { in = Wuv; out = wuvT; R = 2048; C = 512; }
  const int tpc = C >> 6;
  const int r0 = (blockIdx.x / tpc) << 6, c0 = (blockIdx.x % tpc) << 6;
  __shared__ float tile[64][65];
  const int tid = threadIdx.x;
#pragma unroll
  for (int i = 0; i < 4; ++i) {
    int idx = tid + i * 256;                        // 1024 float4 units
    int row = idx >> 4, col4 = (idx & 15) * 4;
    f32x4 v = *(const f32x4*)(in + (size_t)(r0 + row) * C + c0 + col4);
    tile[row][col4] = v[0]; tile[row][col4 + 1] = v[1];
    tile[row][col4 + 2] = v[2]; tile[row][col4 + 3] = v[3];
  }
  __syncthreads();
#pragma unroll
  for (int i = 0; i < 4; ++i) {
    int idx = tid + i * 256;                        // 1024 short4 units
    int crow = idx >> 4, r4 = (idx & 15) * 4;
    short4v o;
    o[0] = f2bf(tile[r4][crow]);     o[1] = f2bf(tile[r4 + 1][crow]);
    o[2] = f2bf(tile[r4 + 2][crow]); o[3] = f2bf(tile[r4 + 3][crow]);
    *(short4v*)(out + (size_t)(c0 + crow) * R + r0 + r4) = o;
  }
}

// vabsT[h][d][l] = vflat[l][h*128+d]  — LDS-tiled. grid (32, 8); 256 threads.
__global__ __launch_bounds__(256) void trans_vabs(const short* __restrict__ in,
                                                  short* __restrict__ out) {
  const int c0 = blockIdx.x << 6, l0 = blockIdx.y << 6;
  __shared__ short tile[64][66];
  const int tid = threadIdx.x;
#pragma unroll
  for (int i = 0; i < 8; ++i) {
    int idx = tid + i * 256;                        // 2048 short2 units
    int row = idx >> 5, col2 = (idx & 31) * 2;
    short2v v = *(const short2v*)(in + (size_t)(l0 + row) * 2048 + c0 + col2);
    tile[row][col2] = v[0]; tile[row][col2 + 1] = v[1];
  }
  __syncthreads();
  const int h = c0 >> 7, d0 = c0 & 127;
  short* ob = out + ((size_t)h << 16) + (size_t)d0 * 512 + l0;
#pragma unroll
  for (int i = 0; i < 8; ++i) {
    int idx = tid + i * 256;
    int crow = idx >> 5, l2 = (idx & 31) * 2;
    short2v v;
    v[0] = tile[l2][crow]; v[1] = tile[l2 + 1][crow];
    *(short2v*)(ob + (size_t)crow * 512 + l2) = v;
  }
}

// ---------------- shared NT GEMM bodies ----------------

__device__ __forceinline__ void gemm128_body(
    const short* A, const short* B, float* Cf, short* Cb,
    int K, int lda, int ldb, int ldc, int bx, int by, float scale)
{
  const int tid = threadIdx.x, wid = tid >> 6, L = tid & 63;
  const int g = L >> 4, r16 = L & 15, wr = wid >> 1, wc = wid & 1;
  const int rl = L >> 3, ru = L & 7;

  __shared__ short Asm[128 * 64], Bsm[128 * 64];
  char* Ab = (char*)Asm;
  char* Bb = (char*)Bsm;

  const f32x4 fz = {0.f, 0.f, 0.f, 0.f};
  f32x4 acc[4][4];
#pragma unroll
  for (int m = 0; m < 4; ++m)
#pragma unroll
    for (int n = 0; n < 4; ++n) acc[m][n] = fz;

  const int aRow0 = bx * 128, bRow0 = by * 128;

  for (int kt = 0; kt < K; kt += 64) {
#pragma unroll
    for (int i = 0; i < 4; ++i) {
      int row = i * 32 + wid * 8 + rl;
      gload_lds16(A + (size_t)(aRow0 + row) * lda + kt + ((ru ^ rl) * 8),
                  Ab + (i * 32 + wid * 8) * 128);
    }
#pragma unroll
    for (int i = 0; i < 4; ++i) {
      int row = i * 32 + wid * 8 + rl;
      gload_lds16(B + (size_t)(bRow0 + row) * ldb + kt + ((ru ^ rl) * 8),
                  Bb + (i * 32 + wid * 8) * 128);
    }
    __syncthreads();
#pragma unroll
    for (int kk = 0; kk < 2; ++kk) {
      short8 a[4], b2[4];
#pragma unroll
      for (int m = 0; m < 4; ++m) {
        int row = wr * 64 + m * 16 + r16;
        a[m] = *(const short8*)(Ab + row * 128 + (((kk * 4 + g) ^ (row & 7)) << 4));
      }
#pragma unroll
      for (int n = 0; n < 4; ++n) {
        int row = wc * 64 + n * 16 + r16;
        b2[n] = *(const short8*)(Bb + row * 128 + (((kk * 4 + g) ^ (row & 7)) << 4));
      }
#pragma unroll
      for (int m = 0; m < 4; ++m)
#pragma unroll
        for (int n = 0; n < 4; ++n) acc[m][n] = mfma16(a[m], b2[n], acc[m][n]);
    }
    __syncthreads();
  }

#pragma unroll
  for (int m = 0; m < 4; ++m) {
    int row0 = aRow0 + wr * 64 + m * 16 + g * 4;
#pragma unroll
    for (int n = 0; n < 4; ++n) {
      int col = bRow0 + wc * 64 + n * 16 + r16;
#pragma unroll
      for (int e = 0; e < 4; ++e) {
        long idx = (long)(row0 + e) * ldc + col;
        float v = acc[m][n][e] * scale;
        if (Cf) Cf[idx] = v;
        if (Cb) Cb[idx] = f2bf(v);
      }
    }
  }
}

__device__ __forceinline__ void gemm64_body(
    const short* A, const short* B, float* Cf, short* Cb,
    int K, int lda, int ldb, int ldc, int bx, int by, float scale)
{
  const int tid = threadIdx.x, wid = tid >> 6, L = tid & 63;
  const int g = L >> 4, r16 = L & 15, wr = wid >> 1, wc = wid & 1;

  __shared__ short Asm[64 * 64], Bsm[64 * 64];
  char* Ab = (char*)Asm;
  char* Bb = (char*)Bsm;

  const f32x4 fz = {0.f, 0.f, 0.f, 0.f};
  f32x4 acc[2][2] = {{fz, fz}, {fz, fz}};
  const int aRow0 = bx * 64, bRow0 = by * 64;

  for (int kt = 0; kt < K; kt += 64) {
#pragma unroll
    for (int i = 0; i < 2; ++i) {
      int ug = i * 256 + wid * 64;
      int row = (ug + L) >> 3, u = (ug + L) & 7;
      gload_lds16(A + (size_t)(aRow0 + row) * lda + kt + ((u ^ (row & 7)) * 8),
                  Ab + ug * 16);
    }
#pragma unroll
    for (int i = 0; i < 2; ++i) {
      int ug = i * 256 + wid * 64;
      int row = (ug + L) >> 3, u = (ug + L) & 7;
      gload_lds16(B + (size_t)(bRow0 + row) * ldb + kt + ((u ^ (row & 7)) * 8),
                  Bb + ug * 16);
    }
    __syncthreads();
#pragma unroll
    for (int kk = 0; kk < 2; ++kk) {
      short8 a[2], b2[2];
#pragma unroll
      for (int m = 0; m < 2; ++m) {
        int row = wr * 32 + m * 16 + r16;
        a[m] = *(const short8*)(Ab + row * 128 + (((kk * 4 + g) ^ (row & 7)) << 4));
      }
#pragma unroll
      for (int n = 0; n < 2; ++n) {
        int row = wc * 32 + n * 16 + r16;
        b2[n] = *(const short8*)(Bb + row * 128 + (((kk * 4 + g) ^ (row & 7)) << 4));
      }
#pragma unroll
      for (int m = 0; m < 2; ++m)
#pragma unroll
        for (int n = 0; n < 2; ++n) acc[m][n] = mfma16(a[m], b2[n], acc[m][n]);
    }
    __syncthreads();
  }

#pragma unroll
  for (int m = 0; m < 2; ++m) {
    int row0 = aRow0 + wr * 32 + m * 16 + g * 4;
#pragma unroll
    for (int n = 0; n < 2; ++n) {
      int col = bRow0 + wc * 32 + n * 16 + r16;
#pragma unroll
      for (int e = 0; e < 4; ++e) {
        long idx = (long)(row0 + e) * ldc + col;
        float v = acc[m][n][e] * scale;
        if (Cf) Cf[idx] = v;
        if (Cb) Cb[idx] = f2bf(v);
      }
    }
  }
}

// ---- fused independent prep GEMMs, 832 x 64² tiles (R11 measured-good config) ----
__global__ __launch_bounds__(256) void gemm_jobs3(
    const short* __restrict__ wukT, const short* __restrict__ wuvT,
    const short* __restrict__ wo, const short* __restrict__ x_bf,
    const short* __restrict__ wdkv,
    short* __restrict__ m1, short* __restrict__ vflat,
    float* __restrict__ ckv_f, short* __restrict__ ckvb)
{
  const int bid = blockIdx.x;
  const short *A, *B; short* Cb; float* Cf; int bx, by, ldc;
  if (bid < 64)       { A = wukT; B = wukT; Cb = m1;    Cf = nullptr;
                        bx = bid >> 3;         by = bid & 7;         ldc = 512; }
  else if (bid < 320) { A = wuvT; B = wo;   Cb = vflat; Cf = nullptr;
                        bx = (bid - 64) >> 5;  by = (bid - 64) & 31; ldc = 2048; }
  else                { A = x_bf; B = wdkv; Cb = ckvb;  Cf = ckv_f;
                        bx = (bid - 320) >> 3; by = (bid - 320) & 7; ldc = 512; }
  gemm64_body(A, B, Cf, Cb, 2048, 2048, 2048, ldc, bx, by, 1.0f);
}

// kabs = W_dq^T @ M1, scale = log2(e)/sqrt(128) folded (flash uses exp2 directly;
// the constant softmax shift cancels exactly in y = acc/l).
__global__ __launch_bounds__(256) void gemm_kabs(
    const short* __restrict__ wdqT, const short* __restrict__ m1,
    short* __restrict__ kabs)
{
  gemm64_body(wdqT, m1, nullptr, kabs, 512, 512, 512, 512,
              blockIdx.x, blockIdx.y, 0.08838834764831845f * 1.4426950408889634f);
}

// ---- fused keff + veff: z<32 -> k_effT[bh][s][d]; z>=32 -> v_effT[bh][d][s] ----
__global__ __launch_bounds__(256) void gemm_keffveff(
    const short* __restrict__ ckvb, const short* __restrict__ kabs,
    const short* __restrict__ vabsT,
    short* __restrict__ keffT, short* __restrict__ veffT)
{
  const int bz = blockIdx.z;
  const short *A, *B; short* C; int ldc, bx, by;
  if (bz < 32) {
    int b = bz >> 4, h = bz & 15;
    A = ckvb + (size_t)b * 2048 * 512;
    B = kabs + (size_t)h * 128 * 512;
    C = keffT + (size_t)bz * 2048 * 128;
    ldc = 128; bx = blockIdx.x; by = 0;
  } else {
    int bh = bz - 32, b = bh >> 4, h = bh & 15;
    A = vabsT + (size_t)h * 128 * 512;
    B = ckvb + (size_t)b * 2048 * 512;
    C = veffT + (size_t)bh * 128 * 2048;
    ldc = 2048; bx = 0; by = blockIdx.x;
  }
  gemm128_body(A, B, nullptr, C, 512, 512, 512, ldc, bx, by, 1.0f);
}

// ---------------- causal flash attention, D=128, high-occupancy 32-key tiles --------
// R13 lesson: occupancy is the binding constraint (m=2 @ 1 WG/CU: 88us; m=1 @ 2 WG/CU:
// 75us). R14: shrink the working set so FOUR WGs co-reside: 32-key kt tiles -> LDS =
// P 4K + 2 x (K 8K + V 8K) = 36.8K -> 4 WG/CU x 4 waves = 16 waves/CU (4/SIMD), 2x
// R12. Grid 1024 = (qt, bh, rowhalf): no pairing; imbalance (2..64 units) handled by
// LPT dispatch order (qt=15 blocks first) + 4-deep per-CU backfill. bh in low 5 bits
// keeps each bh's blocks on one XCD (f%8 = bh%8). VGPR ~95 (R12: 88) -> no spill.
__global__ __launch_bounds__(256) void flash_d128(
    const short* __restrict__ x_bf,  // [2][2048][2048]
    const short* __restrict__ kT,    // [32][2048][128]
    const short* __restrict__ vT,    // [32][128][2048]
    float* __restrict__ y)           // [2][2048][2048]
{
  const int f = blockIdx.x;          // 1024 blocks
  const int bh = f & 31, s_ = f >> 5;
  const int qt = 15 - (s_ >> 1), r = s_ & 1;      // LPT: longest (qt=15) first
  const int b = bh >> 4, h = bh & 15;
  const int tid = threadIdx.x, wid = tid >> 6, L = tid & 63, g = L >> 4, r16 = L & 15;
  const int qw = qt * 128 + r * 64 + wid * 16;    // this wave's 16 q-rows
  const int nkt = 4 * qt + 2 * r + 2;             // 32-key tiles

  __shared__ char lds[36864];        // [P 4x1K][buf0: K 8K | V 8K][buf1: K | V]

  // per-lane staging pointers (two 16B units per array per wave; advance per kt)
  const char* kp0; const char* kp1; const char* vp0; const char* vp1;
  {
    const char* kbase = (const char*)(kT + (size_t)bh * (2048 * 128));
    const char* vbase = (const char*)(vT + (size_t)bh * (128 * 2048));
    int u0 = wid * 128 + L, u1 = u0 + 64;
    int s0u = u0 >> 4, c0u = u0 & 15, s1u = u1 >> 4, c1u = u1 & 15;
    kp0 = kbase + s0u * 256 + ((c0u ^ (s0u & 15)) << 4);
    kp1 = kbase + s1u * 256 + ((c1u ^ (s1u & 15)) << 4);
    int d0u = u0 >> 2, e0u = u0 & 3, d1u = u1 >> 2, e1u = u1 & 3;
    vp0 = vbase + (size_t)d0u * 4096 + ((e0u ^ ((d0u >> 1) & 3)) << 4);
    vp1 = vbase + (size_t)d1u * 4096 + ((e1u ^ ((d1u >> 1) & 3)) << 4);
  }

  // hoisted lane-invariant LDS byte offsets
  int kfo[4], vfo, pao, pwo[4];
#pragma unroll
  for (int ks = 0; ks < 4; ++ks)
    kfo[ks] = 4096 + r16 * 256 + (((ks * 4 + g) ^ r16) << 4);       // + co + n*4096
  vfo = 12288 + r16 * 64 + ((g ^ ((r16 >> 1) & 3)) << 4);           // + co + n*1024
  pao = wid * 1024 + r16 * 64 + ((g ^ ((r16 >> 1) & 3)) << 4);
#pragma unroll
  for (int e = 0; e < 4; ++e) {
    int q = g * 4 + e, q13 = (q >> 1) & 3;
    pwo[e] = wid * 1024 + q * 64 + (((r16 >> 3) ^ q13) << 4) + (r16 & 7) * 2;
  }

  // Q fragments (scale & log2e folded into k_eff)
  short8 qf[4];
#pragma unroll
  for (int ks = 0; ks < 4; ++ks)
    qf[ks] = *(const short8*)(x_bf +
        (size_t)(b * 2048 + qw + r16) * 2048 + h * 128 + ks * 32 + g * 8);

  const f32x4 fz = {0.f, 0.f, 0.f, 0.f};
  f32x4 acc[8];
#pragma unroll
  for (int n = 0; n < 8; ++n) acc[n] = fz;
  f32x4 acc_l = fz;                  // softmax denominator via ones-MFMA

  short8 ones;
#pragma unroll
  for (int i = 0; i < 8; ++i) ones[i] = (short)0x3F80;

  auto stage = [&](int c) {
    char* dstK = lds + 4096 + c * 16384 + wid * 2048;
    gload_lds16(kp0, dstK);
    gload_lds16(kp1, dstK + 1024);
    gload_lds16(vp0, dstK + 8192);
    gload_lds16(vp1, dstK + 9216);
    kp0 += 8192; kp1 += 8192;        // 32 keys * 256B
    vp0 += 64;  vp1 += 64;           // 32 keys * 2B along s
  };

  stage(0);

  for (int kt = 0; kt < nkt; ++kt) {
    const int c = kt & 1, co = c * 16384, s0 = kt * 32;

    if (kt + 1 < nkt) {
      stage(c ^ 1);
      asm volatile("s_waitcnt vmcnt(4)" ::: "memory");  // cur's 4 landed, next 4 fly
    } else {
      asm volatile("s_waitcnt vmcnt(0)" ::: "memory");
    }
    __builtin_amdgcn_s_barrier();

    // QK^T: S[16 q][32 s]
    f32x4 s[2] = {fz, fz};
    __builtin_amdgcn_s_setprio(1);
#pragma unroll
    for (int ks = 0; ks < 4; ++ks) {
      const char* kb = lds + co + kfo[ks];
      s[0] = mfma16(qf[ks], *(const short8*)(kb), s[0]);
      s[1] = mfma16(qf[ks], *(const short8*)(kb + 4096), s[1]);
    }
    __builtin_amdgcn_s_setprio(0);

    if (s0 + 31 > qw) {              // causal mask (straddling / fully-masked tiles)
#pragma unroll
      for (int n = 0; n < 2; ++n)
#pragma unroll
        for (int e = 0; e < 4; ++e)
          if (s0 + n * 16 + r16 > qw + g * 4 + e) s[n][e] = -3e38f;
    }

    // p = exp2(S) (shift-free), pack + LDS write (XOR-decomposed addr)
#pragma unroll
    for (int n = 0; n < 2; ++n)
#pragma unroll
      for (int e = 0; e < 4; ++e) {
        float p = exp2f(s[n][e]);
        *(short*)(lds + (pwo[e] ^ (n << 5))) = f2bf_fast(p);
      }
    short8 pa = *(const short8*)(lds + pao);   // k=32 covers all 32 keys

    // PV + denominator
    __builtin_amdgcn_s_setprio(1);
    acc_l = mfma16(pa, ones, acc_l);
    {
      const char* vb = lds + co + vfo;
#pragma unroll
      for (int n = 0; n < 8; ++n)
        acc[n] = mfma16(pa, *(const short8*)(vb + n * 1024), acc[n]);
    }
    __builtin_amdgcn_s_setprio(0);

    asm volatile("s_waitcnt lgkmcnt(0)" ::: "memory");
    __builtin_amdgcn_s_barrier();    // buf c reusable
  }

  // epilogue: normalize, write y fp32
  float inv[4];
#pragma unroll
  for (int e = 0; e < 4; ++e) inv[e] = 1.f / acc_l[e];
#pragma unroll
  for (int n = 0; n < 8; ++n)
#pragma unroll
    for (int e = 0; e < 4; ++e) {
      int row = qw + g * 4 + e;
      y[(size_t)(b * 2048 + row) * 2048 + h * 128 + n * 16 + r16] =
          acc[n][e] * inv[e];
    }
}

// ---------------- host ----------------

extern "C" void kernel_launch(void* const* d_in, const int* in_sizes, int n_in,
                              void* d_out, int out_size, void* d_ws, size_t ws_size,
                              hipStream_t stream) {
  const float* x    = (const float*)d_in[0];
  const float* Wdq  = (const float*)d_in[1];
  const float* Wdkv = (const float*)d_in[2];
  const float* Wuk  = (const float*)d_in[3];
  const float* Wuv  = (const float*)d_in[4];
  const float* Wo   = (const float*)d_in[5];
  float* y     = (float*)d_out;                        // [2][2048][2048]
  float* ckv_f = y + (size_t)2 * 2048 * 2048;          // [2][2048][512]

  char* w = (char*)d_ws;
  auto alloc = [&](size_t bytes) { char* p = w; w += (bytes + 255) & ~(size_t)255; return p; };
  short* x_bf   = (short*)alloc((size_t)2 * 2048 * 2048 * 2);
  short* wdkv   = (short*)alloc((size_t)512 * 2048 * 2);
  short* wukT   = (short*)alloc((size_t)512 * 2048 * 2);
  short* wdqT   = (short*)alloc((size_t)2048 * 512 * 2);
  short* wuvT   = (short*)alloc((size_t)512 * 2048 * 2);
  short* wo     = (short*)alloc((size_t)2048 * 2048 * 2);
  short* m1     = (short*)alloc((size_t)512 * 512 * 2);
  short* kabs   = (short*)alloc((size_t)2048 * 512 * 2);
  short* vflat  = (short*)alloc((size_t)512 * 2048 * 2);
  short* vabsT  = (short*)alloc((size_t)16 * 128 * 512 * 2);
  short* ckvb   = (short*)alloc((size_t)2 * 2048 * 512 * 2);
  short* keffT  = (short*)alloc((size_t)32 * 2048 * 128 * 2);  // [bh][s][d]
  short* veffT  = (short*)alloc((size_t)32 * 128 * 2048 * 2);  // [bh][d][s]

  conv3<<<13312, 256, 0, stream>>>(x, Wdkv, Wo, x_bf, wdkv, wo);
  trans_w3<<<dim3(256, 3), 256, 0, stream>>>(Wuk, Wdq, Wuv, wukT, wdqT, wuvT);

  // m1 | vflat | c_kv (+ckv_f output chunk) in one launch (832 x 64²)
  gemm_jobs3<<<832, 256, 0, stream>>>(wukT, wuvT, wo, x_bf, wdkv,
                                      m1, vflat, ckv_f, ckvb);
  gemm_kabs<<<dim3(32, 8), 256, 0, stream>>>(wdqT, m1, kabs);
  trans_vabs<<<dim3(32, 8), 256, 0, stream>>>(vflat, vabsT);

  // k_eff + v_eff in one launch
  gemm_keffveff<<<dim3(16, 1, 64), 256, 0, stream>>>(ckvb, kabs, vabsT, keffT, veffT);

  // causal flash attention at D=128 (32-key tiles, 4 WG/CU, LPT grid); writes y fp32
  flash_d128<<<1024, 256, 0, stream>>>(x_bf, keffT, veffT, y);
}